// Round 2
// baseline (899.422 us; speedup 1.0000x reference)
//
#include <hip/hip_runtime.h>
#include <hip/hip_bf16.h>
#include <stdint.h>

typedef float f32x4 __attribute__((ext_vector_type(4)));
typedef __bf16 bf16x8 __attribute__((ext_vector_type(8)));

#define SCALING 1.0f   // lora_alpha / rank = 16/16
#define KR 256         // K*R

static __device__ __forceinline__ void gload_lds16(const void* g, void* l) {
    __builtin_amdgcn_global_load_lds(
        (__attribute__((address_space(1))) void*)(g),
        (__attribute__((address_space(3))) void*)(l), 16, 0, 0);
}

// Ubt[i][k*16+r] = U[k][i][r]  (bf16)
__global__ __launch_bounds__(256) void k_gather_ubt(const float* __restrict__ U,
                                                    __bf16* __restrict__ Ubt) {
    int t = blockIdx.x * 256 + threadIdx.x;     // 32768
    int k = t >> 11, i = t & 2047;
    const float4* s = (const float4*)(U + (size_t)((k << 11) | i) * 16);
    float4 v0 = s[0], v1 = s[1], v2 = s[2], v3 = s[3];
    bf16x8 lo, hi;
    lo[0]=(__bf16)v0.x; lo[1]=(__bf16)v0.y; lo[2]=(__bf16)v0.z; lo[3]=(__bf16)v0.w;
    lo[4]=(__bf16)v1.x; lo[5]=(__bf16)v1.y; lo[6]=(__bf16)v1.z; lo[7]=(__bf16)v1.w;
    hi[0]=(__bf16)v2.x; hi[1]=(__bf16)v2.y; hi[2]=(__bf16)v2.z; hi[3]=(__bf16)v2.w;
    hi[4]=(__bf16)v3.x; hi[5]=(__bf16)v3.y; hi[6]=(__bf16)v3.z; hi[7]=(__bf16)v3.w;
    __bf16* d = Ubt + (size_t)i * KR + k * 16;
    *(bf16x8*)d = lo; *(bf16x8*)(d + 8) = hi;
}

// Pb[b][o][k*16+r] = SCALING*alpha[b][k]*V[k][o][r]  (bf16)
__global__ __launch_bounds__(256) void k_gather_pb(const float* __restrict__ V,
                                                   const float* __restrict__ alpha,
                                                   __bf16* __restrict__ Pb) {
    int t = blockIdx.x * 256 + threadIdx.x;     // 262144
    int b = t >> 15;
    int rem = t & 32767;
    int k = rem >> 11, o = rem & 2047;
    float sc = SCALING * alpha[b * 16 + k];
    const float4* s = (const float4*)(V + (size_t)((k << 11) | o) * 16);
    float4 v0 = s[0], v1 = s[1], v2 = s[2], v3 = s[3];
    bf16x8 lo, hi;
    lo[0]=(__bf16)(v0.x*sc); lo[1]=(__bf16)(v0.y*sc); lo[2]=(__bf16)(v0.z*sc); lo[3]=(__bf16)(v0.w*sc);
    lo[4]=(__bf16)(v1.x*sc); lo[5]=(__bf16)(v1.y*sc); lo[6]=(__bf16)(v1.z*sc); lo[7]=(__bf16)(v1.w*sc);
    hi[0]=(__bf16)(v2.x*sc); hi[1]=(__bf16)(v2.y*sc); hi[2]=(__bf16)(v2.z*sc); hi[3]=(__bf16)(v2.w*sc);
    hi[4]=(__bf16)(v3.x*sc); hi[5]=(__bf16)(v3.y*sc); hi[6]=(__bf16)(v3.z*sc); hi[7]=(__bf16)(v3.w*sc);
    __bf16* d = Pb + (size_t)b * 2048 * KR + (size_t)o * KR + k * 16;
    *(bf16x8*)d = lo; *(bf16x8*)(d + 8) = hi;
}

// Weff[b][o][i] = bf16( W[o][i] + sum_kr Pb[b][o][kr]*Ubt[i][kr] )
// 128x128 tile, BK=32, 4 waves (2x2), K=256 -> 8 iters.
__global__ __launch_bounds__(256) void k_weff(const __bf16* __restrict__ Pb,
                                              const __bf16* __restrict__ Ubt,
                                              const float* __restrict__ W,
                                              __bf16* __restrict__ Weff) {
    const int b = blockIdx.z;
    const int brow = blockIdx.x * 128;   // o
    const int bcol = blockIdx.y * 128;   // i
    const int tid = threadIdx.x, lane = tid & 63, wid = tid >> 6;
    const int wm = wid >> 1, wn = wid & 1;
    __shared__ __align__(16) char smem[32768];
    const __bf16* Ab = Pb + (size_t)b * 2048 * KR;
    f32x4 acc[4][4] = {};
    const int arow = tid >> 2;
    const int acol = (tid & 3) << 3;

    // prologue stage into buf 0
    {
        char* A0 = smem; char* B0 = smem + 8192;
        #pragma unroll
        for (int p = 0; p < 2; ++p) {
            gload_lds16(Ab  + (size_t)(brow + p*64 + arow) * KR + acol, A0 + p*4096 + tid*16);
            gload_lds16(Ubt + (size_t)(bcol + p*64 + arow) * KR + acol, B0 + p*4096 + tid*16);
        }
    }
    __syncthreads();
    int buf = 0;
    for (int t = 0; t < 8; ++t) {
        if (t + 1 < 8) {
            int k0 = (t + 1) << 5;
            char* An = smem + (buf ^ 1) * 16384;
            char* Bn = An + 8192;
            #pragma unroll
            for (int p = 0; p < 2; ++p) {
                gload_lds16(Ab  + (size_t)(brow + p*64 + arow) * KR + k0 + acol, An + p*4096 + tid*16);
                gload_lds16(Ubt + (size_t)(bcol + p*64 + arow) * KR + k0 + acol, Bn + p*4096 + tid*16);
            }
        }
        char* Ac = smem + buf * 16384;
        char* Bc = Ac + 8192;
        const int fr = lane & 15;
        const int fcb = (lane >> 4) << 4;   // byte offset of k-chunk
        bf16x8 af[4], bfr[4];
        #pragma unroll
        for (int mi = 0; mi < 4; ++mi)
            af[mi] = *(const bf16x8*)(Ac + (wm*64 + mi*16 + fr) * 64 + fcb);
        #pragma unroll
        for (int ni = 0; ni < 4; ++ni)
            bfr[ni] = *(const bf16x8*)(Bc + (wn*64 + ni*16 + fr) * 64 + fcb);
        #pragma unroll
        for (int mi = 0; mi < 4; ++mi)
            #pragma unroll
            for (int ni = 0; ni < 4; ++ni)
                acc[mi][ni] = __builtin_amdgcn_mfma_f32_16x16x32_bf16(af[mi], bfr[ni], acc[mi][ni], 0, 0, 0);
        __syncthreads();
        buf ^= 1;
    }
    __bf16* Wout = Weff + (size_t)b * 2048 * 2048;
    const int frow = (lane >> 4) * 4;
    const int fcol = lane & 15;
    #pragma unroll
    for (int mi = 0; mi < 4; ++mi) {
        #pragma unroll
        for (int ni = 0; ni < 4; ++ni) {
            int col = bcol + wn*64 + ni*16 + fcol;
            size_t base = (size_t)(brow + wm*64 + mi*16 + frow) * 2048 + col;
            #pragma unroll
            for (int j = 0; j < 4; ++j)
                Wout[base + (size_t)j * 2048] = (__bf16)(acc[mi][ni][j] + W[base + (size_t)j * 2048]);
        }
    }
}

// Out[m][n] = sum_i x[m][i]*Weff[b][n][i] + bias[n]; m=b*4096+s
// 128x128 tile, BK=32, 64 K-iters; B via global_load_lds, A reg-staged fp32->bf16.
__global__ __launch_bounds__(256) void k_main(const float* __restrict__ X,
                                              const __bf16* __restrict__ Weff,
                                              const float* __restrict__ bias,
                                              float* __restrict__ Out) {
    // XCD-aware swizzle: 4096 blocks, 8 XCDs -> each XCD owns one batch,
    // n-fast within chunk for Weff/x L2 reuse.
    int id = blockIdx.x;
    int xcd = id & 7, sub = id >> 3;
    int nid = xcd * 512 + sub;
    const int by = nid & 15;          // N block
    const int bx = nid >> 4;          // M block
    const int brow = bx * 128;
    const int bcol = by * 128;
    const __bf16* Wb = Weff + (size_t)(brow >> 12) * 2048 * 2048;
    const int tid = threadIdx.x, lane = tid & 63, wid = tid >> 6;
    const int wm = wid >> 1, wn = wid & 1;
    __shared__ __align__(16) char smem[32768];
    f32x4 acc[4][4] = {};
    const int arow = tid >> 2;        // 0..63
    const int acol = (tid & 3) << 3;  // 0,8,16,24

    // prologue: tile 0 into buf 0
    {
        char* A0 = smem; char* B0 = smem + 8192;
        #pragma unroll
        for (int p = 0; p < 2; ++p)
            gload_lds16(Wb + (size_t)(bcol + p*64 + arow) * 2048 + acol, B0 + p*4096 + tid*16);
        #pragma unroll
        for (int p = 0; p < 2; ++p) {
            const float* s = X + (size_t)(brow + p*64 + arow) * 2048 + acol;
            float4 g0 = *(const float4*)s;
            float4 g1 = *(const float4*)(s + 4);
            bf16x8 w;
            w[0]=(__bf16)g0.x; w[1]=(__bf16)g0.y; w[2]=(__bf16)g0.z; w[3]=(__bf16)g0.w;
            w[4]=(__bf16)g1.x; w[5]=(__bf16)g1.y; w[6]=(__bf16)g1.z; w[7]=(__bf16)g1.w;
            *(bf16x8*)(A0 + p*4096 + tid*16) = w;
        }
    }
    __syncthreads();
    int buf = 0;
    for (int t = 0; t < 64; ++t) {
        float4 g[4];
        char* An = smem + (buf ^ 1) * 16384;
        char* Bn = An + 8192;
        if (t + 1 < 64) {
            int k0 = (t + 1) << 5;
            #pragma unroll
            for (int p = 0; p < 2; ++p)
                gload_lds16(Wb + (size_t)(bcol + p*64 + arow) * 2048 + k0 + acol, Bn + p*4096 + tid*16);
            #pragma unroll
            for (int p = 0; p < 2; ++p) {
                const float* s = X + (size_t)(brow + p*64 + arow) * 2048 + k0 + acol;
                g[2*p]   = *(const float4*)s;
                g[2*p+1] = *(const float4*)(s + 4);
            }
        }
        // compute current tile
        char* Ac = smem + buf * 16384;
        char* Bc = Ac + 8192;
        const int fr = lane & 15;
        const int fcb = (lane >> 4) << 4;
        bf16x8 af[4], bfr[4];
        #pragma unroll
        for (int mi = 0; mi < 4; ++mi)
            af[mi] = *(const bf16x8*)(Ac + (wm*64 + mi*16 + fr) * 64 + fcb);
        #pragma unroll
        for (int ni = 0; ni < 4; ++ni)
            bfr[ni] = *(const bf16x8*)(Bc + (wn*64 + ni*16 + fr) * 64 + fcb);
        #pragma unroll
        for (int mi = 0; mi < 4; ++mi)
            #pragma unroll
            for (int ni = 0; ni < 4; ++ni)
                acc[mi][ni] = __builtin_amdgcn_mfma_f32_16x16x32_bf16(af[mi], bfr[ni], acc[mi][ni], 0, 0, 0);
        if (t + 1 < 64) {
            #pragma unroll
            for (int p = 0; p < 2; ++p) {
                bf16x8 w;
                w[0]=(__bf16)g[2*p].x; w[1]=(__bf16)g[2*p].y; w[2]=(__bf16)g[2*p].z; w[3]=(__bf16)g[2*p].w;
                w[4]=(__bf16)g[2*p+1].x; w[5]=(__bf16)g[2*p+1].y; w[6]=(__bf16)g[2*p+1].z; w[7]=(__bf16)g[2*p+1].w;
                *(bf16x8*)(An + p*4096 + tid*16) = w;
            }
        }
        __syncthreads();
        buf ^= 1;
    }
    // epilogue
    const int frow = (lane >> 4) * 4;
    const int fcol = lane & 15;
    #pragma unroll
    for (int mi = 0; mi < 4; ++mi) {
        #pragma unroll
        for (int ni = 0; ni < 4; ++ni) {
            int n = bcol + wn*64 + ni*16 + fcol;
            float bv = bias[n];
            size_t base = (size_t)(brow + wm*64 + mi*16 + frow) * 2048 + n;
            #pragma unroll
            for (int j = 0; j < 4; ++j)
                Out[base + (size_t)j * 2048] = acc[mi][ni][j] + bv;
        }
    }
}

extern "C" void kernel_launch(void* const* d_in, const int* in_sizes, int n_in,
                              void* d_out, int out_size, void* d_ws, size_t ws_size,
                              hipStream_t stream) {
    const float* X     = (const float*)d_in[0];   // (8,4096,2048)
    const float* alpha = (const float*)d_in[1];   // (8,16)
    const float* W     = (const float*)d_in[2];   // (2048,2048)
    const float* bias  = (const float*)d_in[3];   // (2048,)
    const float* U     = (const float*)d_in[4];   // (16,2048,16)
    const float* V     = (const float*)d_in[5];   // (16,2048,16)
    float* Out = (float*)d_out;

    char* ws = (char*)d_ws;
    __bf16* Weff = (__bf16*)ws;                               // 64 MB
    __bf16* Pb   = (__bf16*)(ws + ((size_t)64 << 20));        // 8 MB
    __bf16* Ubt  = (__bf16*)(ws + ((size_t)72 << 20));        // 1 MB

    k_gather_ubt<<<128, 256, 0, stream>>>(U, Ubt);
    k_gather_pb<<<1024, 256, 0, stream>>>(V, alpha, Pb);
    k_weff<<<dim3(16, 16, 8), 256, 0, stream>>>(Pb, Ubt, W, Weff);
    k_main<<<4096, 256, 0, stream>>>(X, Weff, bias, Out);
}